// Round 6
// baseline (406.725 us; speedup 1.0000x reference)
//
#include <hip/hip_runtime.h>
#include <math.h>

// Problem constants
#define B_   8
#define CI_  64
#define CO_  64
#define H_   256
#define W_   256
#define NE_  15
#define RK_  4

typedef __attribute__((ext_vector_type(8))) short short8;   // MFMA A/B frag (8 bf16)
typedef __attribute__((ext_vector_type(4))) float f32x4;    // MFMA C/D frag

__device__ __forceinline__ unsigned bf16u(float f) {
  return (__float_as_uint(f) + 0x8000u) >> 16;              // round-to-nearest-ish
}
__device__ __forceinline__ unsigned pk2(float lo, float hi) {
  return ((__float_as_uint(lo) + 0x8000u) >> 16) |
         ((__float_as_uint(hi) + 0x8000u) & 0xFFFF0000u);
}
__device__ __forceinline__ float ubf(unsigned short u) {
  return __uint_as_float(((unsigned)u) << 16);
}
// async global->LDS DMA, 16B per lane. LDS dest must be wave-uniform base +
// lane*16 (linear); swizzling is done on the GLOBAL source address (rule #21).
__device__ __forceinline__ void gload16(const void* g, void* l) {
  __builtin_amdgcn_global_load_lds(
      (const __attribute__((address_space(1))) unsigned int*)g,
      (__attribute__((address_space(3))) unsigned int*)l, 16, 0, 0);
}

// ---------------------------------------------------------------------------
// Table generation (bf16). All angles reduced exactly mod 256.
// ---------------------------------------------------------------------------
__global__ __launch_bounds__(256) void kTab(unsigned short* __restrict__ TAt,
                                            unsigned short* __restrict__ TB,
                                            unsigned short* __restrict__ TD,
                                            unsigned short* __restrict__ TEt) {
  int idx = blockIdx.x * 256 + threadIdx.x;
  const float C = 6.28318530717958647692f / 256.f;
  if (idx < 32768) {                       // TAt [128][256]
    int n = idx >> 8, q = idx & 255;
    int w = n >> 1, pl = n & 1;
    int mm = (q * w) & 255;
    float s, c; sincosf(C * (float)mm, &s, &c);
    TAt[idx] = (unsigned short)bf16u(pl ? -s : c);
    return;
  }
  idx -= 32768;
  if (idx < 131072) {                      // TB [256][512]
    int mrow = idx >> 9, k = idx & 511;
    int p = k >> 1, tt = k & 1;
    int hr = mrow & 127, imr = mrow >> 7;
    int h = (hr < 64) ? hr : hr + 128;
    int mm = (p * h) & 255;
    float s, c; sincosf(C * (float)mm, &s, &c);
    float v = (imr == 0) ? (tt == 0 ? c : s) : (tt == 0 ? -s : c);
    TB[idx] = (unsigned short)bf16u(v);
    return;
  }
  idx -= 131072;
  if (idx < 131072) {                      // TD [512][256]
    int mrow = idx >> 8, k = idx & 255;
    int hr = k >> 1, tt = k & 1;
    int p = mrow & 255, imr = mrow >> 8;
    int h = (hr < 64) ? hr : hr + 128;
    int mm = (p * h) & 255;
    float s, c; sincosf(C * (float)mm, &s, &c);
    float v = (imr == 0) ? (tt == 0 ? c : -s) : (tt == 0 ? s : c);
    TD[idx] = (unsigned short)bf16u(v);
    return;
  }
  idx -= 131072;
  if (idx < 32768) {                       // TEt [256][128]
    int q = idx >> 7, k = idx & 127;
    int w = k >> 1, pl = k & 1;
    int mm = (q * w) & 255;
    float s, c; sincosf(C * (float)mm, &s, &c);
    float v = (pl == 0) ? ((w == 0 ? 1.f : 2.f * c) / 65536.f)
                        : ((w == 0 ? 0.f : -2.f * s) / 65536.f);
    TEt[idx] = (unsigned short)bf16u(v);
  }
}

// ---------------------------------------------------------------------------
// Fused stages A+B (kAB): per (b,i), 512 blocks x 512 thr.
// Round-6: BK=32 so the staging buffer is 16 KB -> LDS total 49 KB ->
// 3 blocks/CU (was 2). launch_bounds(512,6) targets 24 waves/CU so the
// third block actually schedules. Cross-block overlap hides the per-phase
// vmcnt(0) drain (r5: Occupancy 21.6%, all pipes <10%).
// Swizzle for 64B row stride: chunk slot seg holds source chunk
// seg^((row>>1)&3) -> ds_read_b128 2-way (free).
// LDS: As 16 KB (ph1: x 8K @0 | TAt 8K @8K ; ph2: TB 16K) + XcL 33 KB.
// ---------------------------------------------------------------------------
__global__ __launch_bounds__(512, 6) void kAB(const float* __restrict__ x,
                                              const unsigned short* __restrict__ TAt,
                                              const unsigned short* __restrict__ TB,
                                              unsigned short* __restrict__ Xf) {
  __shared__ unsigned short As[8192];       // 16 KB staging
  __shared__ unsigned short XcL[64 * 264];  // 33 KB (transposed A-result, pad 264)
  int t = threadIdx.x, lane = t & 63, wid = t >> 6;
  int bi = blockIdx.x;
  const float* xb = x + (size_t)bi * 65536;
  int lrow = lane & 15, lk = (lane >> 4) * 8, jhi = lane >> 4;
  f32x4 acc2[2][4];
#pragma unroll
  for (int a = 0; a < 2; ++a)
#pragma unroll
    for (int b = 0; b < 4; ++b) acc2[a][b] = (f32x4){0.f, 0.f, 0.f, 0.f};

  for (int half = 0; half < 2; ++half) {
    // ---- phase 1: C1[m 128][n 128] = x * TAt^T, K=256, BK=32 ----
    f32x4 acc1[2][4];
#pragma unroll
    for (int a = 0; a < 2; ++a)
#pragma unroll
      for (int b = 0; b < 4; ++b) acc1[a][b] = (f32x4){0.f, 0.f, 0.f, 0.f};
    int mb1 = (wid >> 1) * 32, nb1 = (wid & 1) * 64;
    for (int kk = 0; kk < 8; ++kk) {
      int k0 = kk * 32;
      __syncthreads();
      {   // x rows fp32 -> bf16 (reg-staged; needs conversion): 128 x 32
        int r = t >> 2, seg = t & 3;
        int ssw = (seg ^ ((r >> 1) & 3)) * 8;   // source chunk for dest slot seg
        const float* xp = xb + (size_t)(half * 128 + r) * 256 + k0 + ssw;
        float4 v0 = *(const float4*)(xp);
        float4 v1 = *(const float4*)(xp + 4);
        uint4 o;
        o.x = pk2(v0.x, v0.y); o.y = pk2(v0.z, v0.w);
        o.z = pk2(v1.x, v1.y); o.w = pk2(v1.z, v1.w);
        *(uint4*)&As[r * 32 + seg * 8] = o;
        // TAt tile 128x32 via DMA (dest linear = t*16B)
        gload16(&TAt[r * 256 + k0 + ssw], &As[4096 + t * 8]);
      }
      __syncthreads();
      short8 af[2], bf[4];
#pragma unroll
      for (int a = 0; a < 2; ++a) {
        int row = mb1 + a * 16 + lrow;
        af[a] = *(const short8*)&As[row * 32 + ((jhi ^ ((row >> 1) & 3))) * 8];
      }
#pragma unroll
      for (int b = 0; b < 4; ++b) {
        int row = nb1 + b * 16 + lrow;
        bf[b] = *(const short8*)&As[4096 + row * 32 + ((jhi ^ ((row >> 1) & 3))) * 8];
      }
#pragma unroll
      for (int a = 0; a < 2; ++a)
#pragma unroll
        for (int b = 0; b < 4; ++b)
          acc1[a][b] = __builtin_amdgcn_mfma_f32_16x16x32_bf16(af[a], bf[b], acc1[a][b], 0, 0, 0);
    }
    // ---- epilogue 1: transpose into XcL ----
    __syncthreads();   // half=1: all waves done with phase-2 XcL reads
#pragma unroll
    for (int a = 0; a < 2; ++a)
#pragma unroll
      for (int b = 0; b < 4; ++b)
#pragma unroll
        for (int r = 0; r < 4; ++r) {
          int m = mb1 + a * 16 + (lane >> 4) * 4 + r;   // 0..127 within half
          int n = nb1 + b * 16 + lrow;                  // 0..127
          XcL[(n >> 1) * 264 + 2 * m + (n & 1)] = (unsigned short)bf16u(acc1[a][b][r]);
        }
    __syncthreads();
    // ---- phase 2 partial: Xf += TB[:, half*256+k] * XcL, BK=32 ----
    int mb2 = wid * 32;
    for (int kk = 0; kk < 8; ++kk) {
      int k0 = kk * 32;
      __syncthreads();
#pragma unroll
      for (int j = 0; j < 2; ++j) {          // TB tile 256x32 via DMA
        int c = j * 512 + t;
        int m = c >> 2, seg = c & 3;
        int ssw = (seg ^ ((m >> 1) & 3)) * 8;
        gload16(&TB[m * 512 + half * 256 + k0 + ssw], &As[c * 8]);
      }
      __syncthreads();
      short8 af2[2], bf2[4];
#pragma unroll
      for (int a = 0; a < 2; ++a) {
        int row = mb2 + a * 16 + lrow;
        af2[a] = *(const short8*)&As[row * 32 + ((jhi ^ ((row >> 1) & 3))) * 8];
      }
#pragma unroll
      for (int b = 0; b < 4; ++b)
        bf2[b] = *(const short8*)&XcL[(b * 16 + lrow) * 264 + k0 + lk];
#pragma unroll
      for (int a = 0; a < 2; ++a)
#pragma unroll
        for (int b = 0; b < 4; ++b)
          acc2[a][b] = __builtin_amdgcn_mfma_f32_16x16x32_bf16(af2[a], bf2[b], acc2[a][b], 0, 0, 0);
    }
  }
  // ---- epilogue 2: store Xf[b,i][m 256][w 64] ----
  unsigned short* dst = Xf + (size_t)bi * 16384;
#pragma unroll
  for (int a = 0; a < 2; ++a)
#pragma unroll
    for (int b = 0; b < 4; ++b)
#pragma unroll
      for (int r = 0; r < 4; ++r) {
        int m = wid * 32 + a * 16 + (lane >> 4) * 4 + r;
        int n = b * 16 + lrow;
        dst[m * 64 + n] = (unsigned short)bf16u(acc2[a][b][r]);
      }
}

// ---------------------------------------------------------------------------
// Stage C.1 (kT): T[reg][e][b][xy][r] = sum_i la[e,r,i] * X[b,i,cell(e),xy]
// ---------------------------------------------------------------------------
__global__ __launch_bounds__(256) void kT(const unsigned short* __restrict__ Xf,
                                          float2* __restrict__ T,
                                          const float* __restrict__ la1re,
                                          const float* __restrict__ la1im,
                                          const float* __restrict__ la2re,
                                          const float* __restrict__ la2im) {
  int bid = blockIdx.x;
  int b = bid & 7;
  int e = (bid >> 3) % 15;
  int reg = bid / 120;
  int ep1 = e + 1;
  int grr = (reg == 0) ? (ep1 >> 2) : (3 - (ep1 >> 2));
  int gc = ep1 & 3;
  int hr0 = reg * 64 + grr * 16;
  int w0 = gc * 16;
  int t = threadIdx.x;
  int xx = t >> 4, yy = t & 15;
  const unsigned short* xp =
      Xf + (size_t)b * 64 * 16384 + (hr0 + xx) * 64 + (w0 + yy);
  const float* lare = (reg == 0) ? la1re : la2re;
  const float* laim = (reg == 0) ? la1im : la2im;
  float ar0 = 0.f, ai0 = 0.f, ar1 = 0.f, ai1 = 0.f;
  float ar2 = 0.f, ai2 = 0.f, ar3 = 0.f, ai3 = 0.f;
#pragma unroll 8
  for (int i = 0; i < 64; ++i) {
    float xr = ubf(xp[(size_t)i * 16384]);
    float xi = ubf(xp[(size_t)i * 16384 + 8192]);
    float l0r = lare[(e * 4 + 0) * 64 + i], l0i = laim[(e * 4 + 0) * 64 + i];
    float l1r = lare[(e * 4 + 1) * 64 + i], l1i = laim[(e * 4 + 1) * 64 + i];
    float l2r = lare[(e * 4 + 2) * 64 + i], l2i = laim[(e * 4 + 2) * 64 + i];
    float l3r = lare[(e * 4 + 3) * 64 + i], l3i = laim[(e * 4 + 3) * 64 + i];
    ar0 += l0r * xr - l0i * xi; ai0 += l0r * xi + l0i * xr;
    ar1 += l1r * xr - l1i * xi; ai1 += l1r * xi + l1i * xr;
    ar2 += l2r * xr - l2i * xi; ai2 += l2r * xi + l2i * xr;
    ar3 += l3r * xr - l3i * xi; ai3 += l3r * xi + l3i * xr;
  }
  float2* dst = T + ((((size_t)reg * 15 + e) * 8 + b) * 256 + t) * 4;
  dst[0] = make_float2(ar0, ai0);
  dst[1] = make_float2(ar1, ai1);
  dst[2] = make_float2(ar2, ai2);
  dst[3] = make_float2(ar3, ai3);
}

// ---------------------------------------------------------------------------
// Fused stage C.2 + C.3 (kDM): blocks [0,256) run the dense-corner body (kD),
// blocks [256,768) run the LoRA body (kM). Bodies unchanged (bit-identical).
// ---------------------------------------------------------------------------
__global__ __launch_bounds__(256) void kDM(const unsigned short* __restrict__ Xf,
                                           const float2* __restrict__ T,
                                           unsigned short* __restrict__ Gt,
                                           const float* __restrict__ w1re,
                                           const float* __restrict__ w1im,
                                           const float* __restrict__ w2re,
                                           const float* __restrict__ w2im,
                                           const float* __restrict__ lb1re,
                                           const float* __restrict__ lb1im,
                                           const float* __restrict__ lb2re,
                                           const float* __restrict__ lb2im,
                                           const float* __restrict__ gate1,
                                           const float* __restrict__ gate2) {
  __shared__ unsigned Xs[32 * 4 * 8 * 8];    // 32 KB (used by dense body only)
  if (blockIdx.x < 256) {
    // ---- dense body (kD) ----
    int bid = blockIdx.x;
    int yc = bid & 1, xc = (bid >> 1) & 3, oc = (bid >> 3) & 15, reg = bid >> 7;
    int hrb = (reg == 0) ? xc * 4 : 112 + xc * 4;
    const float* Wre = (reg == 0) ? w1re : w2re;
    const float* Wim = (reg == 0) ? w1im : w2im;
    int t = threadIdx.x;
    int b = t >> 5, o = (t >> 3) & 3, yy = t & 7;
    int og = oc * 4 + o, yyg = yc * 8 + yy;
    float ar[4] = {0.f, 0.f, 0.f, 0.f}, ai[4] = {0.f, 0.f, 0.f, 0.f};
    for (int ch = 0; ch < 2; ++ch) {
      __syncthreads();
#pragma unroll
      for (int j = 0; j < 4; ++j) {
        int seg = t + j * 256;               // 0..1023 = (sb 8, sx 4, si 32)
        int sb = seg >> 7, sx = (seg >> 5) & 3, si = seg & 31;
        int i = ch * 32 + si;
        const unsigned short* p =
            Xf + (size_t)(sb * 64 + i) * 16384 + (hrb + sx) * 64 + yc * 8;
        uint4 re = *(const uint4*)p;          // 8 yy re
        uint4 im = *(const uint4*)(p + 8192); // 8 yy im
        uint4 o0, o1;
        o0.x = (re.x & 0xFFFFu) | (im.x << 16);
        o0.y = (re.x >> 16) | (im.x & 0xFFFF0000u);
        o0.z = (re.y & 0xFFFFu) | (im.y << 16);
        o0.w = (re.y >> 16) | (im.y & 0xFFFF0000u);
        o1.x = (re.z & 0xFFFFu) | (im.z << 16);
        o1.y = (re.z >> 16) | (im.z & 0xFFFF0000u);
        o1.z = (re.w & 0xFFFFu) | (im.w << 16);
        o1.w = (re.w >> 16) | (im.w & 0xFFFF0000u);
        uint4* d = (uint4*)&Xs[((si * 4 + sx) * 8 + sb) * 8];
        d[0] = o0; d[1] = o1;
      }
      __syncthreads();
      for (int ic = 0; ic < 32; ++ic) {
        int i = ch * 32 + ic;
#pragma unroll
        for (int xs = 0; xs < 4; ++xs) {
          unsigned pk = Xs[((ic * 4 + xs) * 8 + b) * 8 + yy];
          float xr = ubf((unsigned short)(pk & 0xFFFFu));
          float xi = ubf((unsigned short)(pk >> 16));
          int widx = ((i * 64 + og) * 16 + xc * 4 + xs) * 16 + yyg;
          float wr = Wre[widx], wi = Wim[widx];
          ar[xs] += xr * wr - xi * wi;
          ai[xs] += xr * wi + xi * wr;
        }
      }
    }
    uint4 ov;
    ov.x = pk2(ar[0], ai[0]);
    ov.y = pk2(ar[1], ai[1]);
    ov.z = pk2(ar[2], ai[2]);
    ov.w = pk2(ar[3], ai[3]);
    *(uint4*)(Gt + ((size_t)(b * 64 + og) * 64 + yyg) * 256 + 2 * hrb) = ov;
  } else {
    // ---- LoRA body (kM) ----
    int bid = blockIdx.x - 256;
    int xc = bid & 3, hrc = (bid >> 2) & 7, oc = bid >> 5;
    int t = threadIdx.x;
    int w = t & 63, og = t >> 6;
    int o = oc * 4 + og;
    int reg = hrc >> 2;
    int grr = hrc & 3;
    int gc = w >> 4, yy = w & 15;
    int e = (reg == 0) ? (4 * grr + gc - 1) : (4 * (3 - grr) + gc - 1);
    if (e < 0) return;                       // dense cell -> dense body writes it
    float gate = (reg == 0) ? gate1[e] : gate2[e];
    float g = 0.1f / (1.f + __expf(-gate));
    const float* lbre = (reg == 0) ? lb1re : lb2re;
    const float* lbim = (reg == 0) ? lb1im : lb2im;
    size_t lbb = ((size_t)(e * 64 + o) * 4) * 256 + yy;
    float blr[4][4], bli[4][4];
#pragma unroll
    for (int x2 = 0; x2 < 4; ++x2) {
      int xx = xc * 4 + x2;
      const float* pr = lbre + lbb + xx * 16;
      const float* pi = lbim + lbb + xx * 16;
#pragma unroll
      for (int r = 0; r < 4; ++r) {
        blr[x2][r] = pr[r * 256];
        bli[x2][r] = pi[r * 256];
      }
    }
    const size_t tbase = (((size_t)reg * 15 + e) * 8) * 256 + yy;
    for (int b = 0; b < 8; ++b) {
      const float4* tp = (const float4*)(T + (tbase + (size_t)b * 256) * 4);
      unsigned out4[4];
#pragma unroll
      for (int x2 = 0; x2 < 4; ++x2) {
        int xx = xc * 4 + x2;
        float4 t01 = tp[xx * 32];            // r0, r1 (re,im pairs)
        float4 t23 = tp[xx * 32 + 1];        // r2, r3
        float ar = 0.f, aim = 0.f;
        ar += t01.x * blr[x2][0] - t01.y * bli[x2][0];
        aim += t01.x * bli[x2][0] + t01.y * blr[x2][0];
        ar += t01.z * blr[x2][1] - t01.w * bli[x2][1];
        aim += t01.z * bli[x2][1] + t01.w * blr[x2][1];
        ar += t23.x * blr[x2][2] - t23.y * bli[x2][2];
        aim += t23.x * bli[x2][2] + t23.y * blr[x2][2];
        ar += t23.z * blr[x2][3] - t23.w * bli[x2][3];
        aim += t23.z * bli[x2][3] + t23.w * blr[x2][3];
        out4[x2] = pk2(g * ar, g * aim);
      }
      *(uint4*)(Gt + ((size_t)(b * 64 + o) * 64 + w) * 256 + hrc * 32 + xc * 8) =
          make_uint4(out4[0], out4[1], out4[2], out4[3]);
    }
  }
}

// ---------------------------------------------------------------------------
// Fused stages D+E (kDE): per (b,o), 512 blocks x 512 thr. LDS-staged with
// DMA + source-side XOR swizzle. Gt stage issued before TD stage so its
// latency overlaps the TD DMA burst. ZL aliases the phase-1 staging buffers.
// LDS 76 KB -> 2 blocks/CU.
// ---------------------------------------------------------------------------
__global__ __launch_bounds__(512) void kDE(const unsigned short* __restrict__ Gt,
                                           const unsigned short* __restrict__ TD,
                                           const unsigned short* __restrict__ TEt,
                                           float* __restrict__ y) {
  __shared__ __align__(16) char smem[77824];
  unsigned short* As  = (unsigned short*)smem;            // [512*32]  32 KB (phase 1)
  unsigned short* Bs  = (unsigned short*)(smem + 32768);  // [64*32]    4 KB (phase 1)
  unsigned short* ZL  = (unsigned short*)smem;            // [256*136] 68 KB (phase 2, aliases As/Bs)
  unsigned short* Bs2 = (unsigned short*)(smem + 69632);  // [128*32]   8 KB (phase 2)
  int t = threadIdx.x, lane = t & 63, wid = t >> 6;
  int bo = blockIdx.x;
  const unsigned short* Grow = Gt + (size_t)bo * 16384;
  int lrow = lane & 15, lk = (lane >> 4) * 8, jhi = lane >> 4;

  // ---- phase 1: Z = TD * Gt ----
  {
    int mb = wid * 64;
    f32x4 acc[4][4];
#pragma unroll
    for (int a = 0; a < 4; ++a)
#pragma unroll
      for (int b = 0; b < 4; ++b) acc[a][b] = (f32x4){0.f, 0.f, 0.f, 0.f};
    for (int kk = 0; kk < 8; ++kk) {
      int k0 = kk * 32;
      __syncthreads();
      if (t < 256) {                           // Gt tile 64x32 via DMA (first: overlap)
        int n = t >> 2, seg = t & 3;
        gload16(&Grow[n * 256 + k0 + ((seg ^ (n & 3))) * 8], &Bs[t * 8]);
      }
#pragma unroll
      for (int j = 0; j < 4; ++j) {            // TD tile 512x32 via DMA
        int c = j * 512 + t;
        int m = c >> 2, seg = c & 3;
        gload16(&TD[m * 256 + k0 + ((seg ^ (m & 3))) * 8], &As[c * 8]);
      }
      __syncthreads();
      short8 af[4], bf[4];
#pragma unroll
      for (int a = 0; a < 4; ++a) {
        int row = mb + a * 16 + lrow;
        af[a] = *(const short8*)&As[row * 32 + ((jhi ^ (row & 3))) * 8];
      }
#pragma unroll
      for (int b = 0; b < 4; ++b) {
        int row = b * 16 + lrow;
        bf[b] = *(const short8*)&Bs[row * 32 + ((jhi ^ (row & 3))) * 8];
      }
#pragma unroll
      for (int a = 0; a < 4; ++a)
#pragma unroll
        for (int b = 0; b < 4; ++b)
          acc[a][b] = __builtin_amdgcn_mfma_f32_16x16x32_bf16(af[a], bf[b], acc[a][b], 0, 0, 0);
    }
    // write Z (bf16) into ZL[p][k=2w+pl], stride 136 (As/Bs dead after barrier)
    __syncthreads();
#pragma unroll
    for (int a = 0; a < 4; ++a)
#pragma unroll
      for (int b = 0; b < 4; ++b)
#pragma unroll
        for (int r = 0; r < 4; ++r) {
          int m = mb + a * 16 + (lane >> 4) * 4 + r;
          int p = m & 255, pl = m >> 8;
          int n = b * 16 + lrow;
          ZL[p * 136 + 2 * n + pl] = (unsigned short)bf16u(acc[a][b][r]);
        }
    __syncthreads();
  }

  // ---- phase 2: y = ZL * TEt^T, qh in {0,1} ----
  int mb2 = (wid >> 1) * 64, nb2 = (wid & 1) * 64;
  for (int qh = 0; qh < 2; ++qh) {
    f32x4 acc[4][4];
#pragma unroll
    for (int a = 0; a < 4; ++a)
#pragma unroll
      for (int b = 0; b < 4; ++b) acc[a][b] = (f32x4){0.f, 0.f, 0.f, 0.f};
    for (int kk = 0; kk < 4; ++kk) {
      int k0 = kk * 32;
      __syncthreads();
      {                                        // TEt tile 128x32 via DMA
        int n = t >> 2, seg = t & 3;
        gload16(&TEt[(qh * 128 + n) * 128 + k0 + ((seg ^ (n & 3))) * 8], &Bs2[t * 8]);
      }
      __syncthreads();
      short8 af[4], bf[4];
#pragma unroll
      for (int a = 0; a < 4; ++a)
        af[a] = *(const short8*)&ZL[(mb2 + a * 16 + lrow) * 136 + k0 + lk];
#pragma unroll
      for (int b = 0; b < 4; ++b) {
        int row = nb2 + b * 16 + lrow;
        bf[b] = *(const short8*)&Bs2[row * 32 + ((jhi ^ (row & 3))) * 8];
      }
#pragma unroll
      for (int a = 0; a < 4; ++a)
#pragma unroll
        for (int b = 0; b < 4; ++b)
          acc[a][b] = __builtin_amdgcn_mfma_f32_16x16x32_bf16(af[a], bf[b], acc[a][b], 0, 0, 0);
    }
    float* dst = y + (size_t)bo * 65536 + qh * 128;
#pragma unroll
    for (int a = 0; a < 4; ++a)
#pragma unroll
      for (int b = 0; b < 4; ++b)
#pragma unroll
        for (int r = 0; r < 4; ++r) {
          int p = mb2 + a * 16 + (lane >> 4) * 4 + r;
          int q = nb2 + b * 16 + lrow;
          dst[(size_t)p * 256 + q] = acc[a][b][r];
        }
  }
}

// ---------------------------------------------------------------------------
// sploss = mean(sigmoid(gate1)) + mean(sigmoid(gate2))  (fp32)
// ---------------------------------------------------------------------------
__global__ void kS2(const float* __restrict__ gate1, const float* __restrict__ gate2,
                    float* __restrict__ out) {
  if (threadIdx.x == 0) {
    float s = 0.f;
    for (int e = 0; e < NE_; ++e)
      s += 1.f / (1.f + expf(-gate1[e])) + 1.f / (1.f + expf(-gate2[e]));
    out[0] = s / (float)NE_;
  }
}

extern "C" void kernel_launch(void* const* d_in, const int* in_sizes, int n_in,
                              void* d_out, int out_size, void* d_ws, size_t ws_size,
                              hipStream_t stream) {
  const float* x     = (const float*)d_in[0];
  const float* w1re  = (const float*)d_in[1];
  const float* w1im  = (const float*)d_in[2];
  const float* w2re  = (const float*)d_in[3];
  const float* w2im  = (const float*)d_in[4];
  const float* la1re = (const float*)d_in[5];
  const float* la1im = (const float*)d_in[6];
  const float* lb1re = (const float*)d_in[7];
  const float* lb1im = (const float*)d_in[8];
  const float* la2re = (const float*)d_in[9];
  const float* la2im = (const float*)d_in[10];
  const float* lb2re = (const float*)d_in[11];
  const float* lb2im = (const float*)d_in[12];
  const float* gate1 = (const float*)d_in[13];
  const float* gate2 = (const float*)d_in[14];

  // Workspace layout (bf16 halfwords):
  //   Xf  @ 32 MiB : [b,i][m=hr-plane 256][w 64] 16 MiB
  //   Gt  @ 48 MiB : [b,o][w 64][k=2hr+pl 256]   16 MiB
  //   tables @ 96 MiB : TAt 64K, TB 256K, TD 256K, TEt 64K  (1.25 MiB)
  //   T   @ 97 MiB : [reg][e][b][xy][r] float2   ~2 MiB
  char* ws = (char*)d_ws;
  unsigned short* Xf  = (unsigned short*)(ws + ((size_t)32 << 20));
  unsigned short* Gt  = (unsigned short*)(ws + ((size_t)48 << 20));
  unsigned short* TAt = (unsigned short*)(ws + ((size_t)96 << 20));
  unsigned short* TB  = TAt + 32768;
  unsigned short* TD  = TB + 131072;
  unsigned short* TEt = TD + 131072;
  float2* Tw = (float2*)(ws + ((size_t)97 << 20));
  float* y = (float*)d_out;

  kTab<<<1280, 256, 0, stream>>>(TAt, TB, TD, TEt);
  kAB<<<512, 512, 0, stream>>>(x, TAt, TB, Xf);
  kT<<<240, 256, 0, stream>>>(Xf, Tw, la1re, la1im, la2re, la2im);
  kDM<<<768, 256, 0, stream>>>(Xf, Tw, Gt, w1re, w1im, w2re, w2im,
                               lb1re, lb1im, lb2re, lb2im, gate1, gate2);
  kDE<<<512, 512, 0, stream>>>(Gt, TD, TEt, y);
  kS2<<<1, 64, 0, stream>>>(gate1, gate2, y + (size_t)B_ * CO_ * H_ * W_);
}

// Round 7
// 379.825 us; speedup vs baseline: 1.0708x; 1.0708x over previous
//
#include <hip/hip_runtime.h>
#include <math.h>

// Problem constants
#define B_   8
#define CI_  64
#define CO_  64
#define H_   256
#define W_   256
#define NE_  15
#define RK_  4

typedef __attribute__((ext_vector_type(8))) short short8;   // MFMA A/B frag (8 bf16)
typedef __attribute__((ext_vector_type(4))) float f32x4;    // MFMA C/D frag

__device__ __forceinline__ unsigned bf16u(float f) {
  return (__float_as_uint(f) + 0x8000u) >> 16;              // round-to-nearest-ish
}
__device__ __forceinline__ unsigned pk2(float lo, float hi) {
  return ((__float_as_uint(lo) + 0x8000u) >> 16) |
         ((__float_as_uint(hi) + 0x8000u) & 0xFFFF0000u);
}
__device__ __forceinline__ float ubf(unsigned short u) {
  return __uint_as_float(((unsigned)u) << 16);
}
// async global->LDS DMA, 16B per lane. LDS dest must be wave-uniform base +
// lane*16 (linear); swizzling is done on the GLOBAL source address (rule #21).
__device__ __forceinline__ void gload16(const void* g, void* l) {
  __builtin_amdgcn_global_load_lds(
      (const __attribute__((address_space(1))) unsigned int*)g,
      (__attribute__((address_space(3))) unsigned int*)l, 16, 0, 0);
}

// ---------------------------------------------------------------------------
// Table generation (bf16). All angles reduced exactly mod 256.
// ---------------------------------------------------------------------------
__global__ __launch_bounds__(256) void kTab(unsigned short* __restrict__ TAt,
                                            unsigned short* __restrict__ TB,
                                            unsigned short* __restrict__ TD,
                                            unsigned short* __restrict__ TEt) {
  int idx = blockIdx.x * 256 + threadIdx.x;
  const float C = 6.28318530717958647692f / 256.f;
  if (idx < 32768) {                       // TAt [128][256]
    int n = idx >> 8, q = idx & 255;
    int w = n >> 1, pl = n & 1;
    int mm = (q * w) & 255;
    float s, c; sincosf(C * (float)mm, &s, &c);
    TAt[idx] = (unsigned short)bf16u(pl ? -s : c);
    return;
  }
  idx -= 32768;
  if (idx < 131072) {                      // TB [256][512]
    int mrow = idx >> 9, k = idx & 511;
    int p = k >> 1, tt = k & 1;
    int hr = mrow & 127, imr = mrow >> 7;
    int h = (hr < 64) ? hr : hr + 128;
    int mm = (p * h) & 255;
    float s, c; sincosf(C * (float)mm, &s, &c);
    float v = (imr == 0) ? (tt == 0 ? c : s) : (tt == 0 ? -s : c);
    TB[idx] = (unsigned short)bf16u(v);
    return;
  }
  idx -= 131072;
  if (idx < 131072) {                      // TD [512][256]
    int mrow = idx >> 8, k = idx & 255;
    int hr = k >> 1, tt = k & 1;
    int p = mrow & 255, imr = mrow >> 8;
    int h = (hr < 64) ? hr : hr + 128;
    int mm = (p * h) & 255;
    float s, c; sincosf(C * (float)mm, &s, &c);
    float v = (imr == 0) ? (tt == 0 ? c : -s) : (tt == 0 ? s : c);
    TD[idx] = (unsigned short)bf16u(v);
    return;
  }
  idx -= 131072;
  if (idx < 32768) {                       // TEt [256][128]
    int q = idx >> 7, k = idx & 127;
    int w = k >> 1, pl = k & 1;
    int mm = (q * w) & 255;
    float s, c; sincosf(C * (float)mm, &s, &c);
    float v = (pl == 0) ? ((w == 0 ? 1.f : 2.f * c) / 65536.f)
                        : ((w == 0 ? 0.f : -2.f * s) / 65536.f);
    TEt[idx] = (unsigned short)bf16u(v);
  }
}

// ---------------------------------------------------------------------------
// Fused stages A+B (kAB): per (b,i), 512 blocks x 512 thr.
// Round-7: counted-vmcnt double-buffered staging (m201 pattern). Per K-step:
//   BAR_A -> issue stage(kk+1) into buf^1 -> s_waitcnt vmcnt(N)+lgkmcnt(0)
//   -> BAR_B -> ds_read buf[cur] + MFMA.
// vmcnt never drains to 0 in steady state; raw s_barrier (no compiler drain).
// Buffer safety: buf^1's last readers (iter kk-1) all finished before BAR_A.
// BK=32, 2 bufs x 16KB (x 8K | TAt 8K ; TB flat 16K) + XcL 33K = 65 KB
//   -> 2 blocks/CU. VGPR unconstrained (r6 lesson: forcing 40 VGPR spills).
// ---------------------------------------------------------------------------
__global__ __launch_bounds__(512) void kAB(const float* __restrict__ x,
                                           const unsigned short* __restrict__ TAt,
                                           const unsigned short* __restrict__ TB,
                                           unsigned short* __restrict__ Xf) {
  __shared__ unsigned short S[2][8192];     // 2 x 16 KB staging
  __shared__ unsigned short XcL[64 * 264];  // 33 KB (transposed A-result, pad 264)
  int t = threadIdx.x, lane = t & 63, wid = t >> 6;
  int bi = blockIdx.x;
  const float* xb = x + (size_t)bi * 65536;
  int lrow = lane & 15, lk = (lane >> 4) * 8, jhi = lane >> 4;
  int rs = t >> 2, sg = t & 3;
  int ssw = (sg ^ ((rs >> 1) & 3)) * 8;     // source chunk for dest slot sg
  f32x4 acc2[2][4];
#pragma unroll
  for (int a = 0; a < 2; ++a)
#pragma unroll
    for (int b = 0; b < 4; ++b) acc2[a][b] = (f32x4){0.f, 0.f, 0.f, 0.f};

  for (int half = 0; half < 2; ++half) {
    // ================= phase 1: C1 = x * TAt^T, K=256, BK=32 =================
    f32x4 acc1[2][4];
#pragma unroll
    for (int a = 0; a < 2; ++a)
#pragma unroll
      for (int b = 0; b < 4; ++b) acc1[a][b] = (f32x4){0.f, 0.f, 0.f, 0.f};
    int mb1 = (wid >> 1) * 32, nb1 = (wid & 1) * 64;
    const float* xrowp = xb + (size_t)(half * 128 + rs) * 256 + ssw;
    // prologue: x(0) regs + TAt(0) DMA -> S0
    float4 xv0 = *(const float4*)(xrowp);
    float4 xv1 = *(const float4*)(xrowp + 4);
    asm volatile("" ::: "memory");
    gload16(&TAt[rs * 256 + ssw], &S[0][4096 + t * 8]);
#pragma unroll
    for (int kk = 0; kk < 8; ++kk) {
      int cur = kk & 1;
      __builtin_amdgcn_s_barrier();                 // BAR_A
      __builtin_amdgcn_sched_barrier(0);
      {   // convert + ds_write x(kk) -> S[cur].xA (compiler waits xv regs)
        uint4 o;
        o.x = pk2(xv0.x, xv0.y); o.y = pk2(xv0.z, xv0.w);
        o.z = pk2(xv1.x, xv1.y); o.w = pk2(xv1.z, xv1.w);
        *(uint4*)&S[cur][rs * 32 + sg * 8] = o;
      }
      if (kk < 7) {
        int k1 = (kk + 1) * 32;
        xv0 = *(const float4*)(xrowp + k1);         // x(kk+1) -> regs
        xv1 = *(const float4*)(xrowp + k1 + 4);
        asm volatile("" ::: "memory");
        gload16(&TAt[rs * 256 + k1 + ssw], &S[cur ^ 1][4096 + t * 8]);
        asm volatile("s_waitcnt vmcnt(3)" ::: "memory");  // TAt(kk) landed; kk+1 in flight
      } else {
        asm volatile("s_waitcnt vmcnt(0)" ::: "memory");
      }
      asm volatile("s_waitcnt lgkmcnt(0)" ::: "memory");  // own ds_write done
      __builtin_amdgcn_sched_barrier(0);
      __builtin_amdgcn_s_barrier();                 // BAR_B: S[cur] published
      __builtin_amdgcn_sched_barrier(0);
      short8 af[2], bf[4];
#pragma unroll
      for (int a = 0; a < 2; ++a) {
        int row = mb1 + a * 16 + lrow;
        af[a] = *(const short8*)&S[cur][row * 32 + ((jhi ^ ((row >> 1) & 3))) * 8];
      }
#pragma unroll
      for (int b = 0; b < 4; ++b) {
        int row = nb1 + b * 16 + lrow;
        bf[b] = *(const short8*)&S[cur][4096 + row * 32 + ((jhi ^ ((row >> 1) & 3))) * 8];
      }
#pragma unroll
      for (int a = 0; a < 2; ++a)
#pragma unroll
        for (int b = 0; b < 4; ++b)
          acc1[a][b] = __builtin_amdgcn_mfma_f32_16x16x32_bf16(af[a], bf[b], acc1[a][b], 0, 0, 0);
    }
    // ---- epilogue 1: transpose into XcL (full drain is fine here) ----
    __syncthreads();   // half=1: all waves done with phase-2 XcL reads
#pragma unroll
    for (int a = 0; a < 2; ++a)
#pragma unroll
      for (int b = 0; b < 4; ++b)
#pragma unroll
        for (int r = 0; r < 4; ++r) {
          int m = mb1 + a * 16 + (lane >> 4) * 4 + r;   // 0..127 within half
          int n = nb1 + b * 16 + lrow;                  // 0..127
          XcL[(n >> 1) * 264 + 2 * m + (n & 1)] = (unsigned short)bf16u(acc1[a][b][r]);
        }
    __syncthreads();
    // ================= phase 2: Xf += TB[:, half*256+k] * XcL ================
    int mb2 = wid * 32;
    // prologue: TB(0) -> S0 (2 gload16/thread)
#pragma unroll
    for (int j = 0; j < 2; ++j) {
      int c = j * 512 + t;
      int m = c >> 2, s2 = c & 3;
      gload16(&TB[m * 512 + half * 256 + ((s2 ^ ((m >> 1) & 3))) * 8], &S[0][c * 8]);
    }
#pragma unroll
    for (int kk = 0; kk < 8; ++kk) {
      int cur = kk & 1;
      __builtin_amdgcn_s_barrier();                 // BAR_A
      __builtin_amdgcn_sched_barrier(0);
      if (kk < 7) {
        int k1 = (kk + 1) * 32;
#pragma unroll
        for (int j = 0; j < 2; ++j) {
          int c = j * 512 + t;
          int m = c >> 2, s2 = c & 3;
          gload16(&TB[m * 512 + half * 256 + k1 + ((s2 ^ ((m >> 1) & 3))) * 8],
                  &S[cur ^ 1][c * 8]);
        }
        asm volatile("s_waitcnt vmcnt(2)" ::: "memory");  // TB(kk) landed
      } else {
        asm volatile("s_waitcnt vmcnt(0)" ::: "memory");
      }
      __builtin_amdgcn_sched_barrier(0);
      __builtin_amdgcn_s_barrier();                 // BAR_B
      __builtin_amdgcn_sched_barrier(0);
      int k0 = kk * 32;
      short8 af2[2], bf2[4];
#pragma unroll
      for (int a = 0; a < 2; ++a) {
        int row = mb2 + a * 16 + lrow;
        af2[a] = *(const short8*)&S[cur][row * 32 + ((jhi ^ ((row >> 1) & 3))) * 8];
      }
#pragma unroll
      for (int b = 0; b < 4; ++b)
        bf2[b] = *(const short8*)&XcL[(b * 16 + lrow) * 264 + k0 + lk];
#pragma unroll
      for (int a = 0; a < 2; ++a)
#pragma unroll
        for (int b = 0; b < 4; ++b)
          acc2[a][b] = __builtin_amdgcn_mfma_f32_16x16x32_bf16(af2[a], bf2[b], acc2[a][b], 0, 0, 0);
    }
  }
  // ---- epilogue 2: store Xf[b,i][m 256][w 64] ----
  unsigned short* dst = Xf + (size_t)bi * 16384;
#pragma unroll
  for (int a = 0; a < 2; ++a)
#pragma unroll
    for (int b = 0; b < 4; ++b)
#pragma unroll
      for (int r = 0; r < 4; ++r) {
        int m = wid * 32 + a * 16 + (lane >> 4) * 4 + r;
        int n = b * 16 + lrow;
        dst[m * 64 + n] = (unsigned short)bf16u(acc2[a][b][r]);
      }
}

// ---------------------------------------------------------------------------
// Stage C.1 (kT): T[reg][e][b][xy][r] = sum_i la[e,r,i] * X[b,i,cell(e),xy]
// ---------------------------------------------------------------------------
__global__ __launch_bounds__(256) void kT(const unsigned short* __restrict__ Xf,
                                          float2* __restrict__ T,
                                          const float* __restrict__ la1re,
                                          const float* __restrict__ la1im,
                                          const float* __restrict__ la2re,
                                          const float* __restrict__ la2im) {
  int bid = blockIdx.x;
  int b = bid & 7;
  int e = (bid >> 3) % 15;
  int reg = bid / 120;
  int ep1 = e + 1;
  int grr = (reg == 0) ? (ep1 >> 2) : (3 - (ep1 >> 2));
  int gc = ep1 & 3;
  int hr0 = reg * 64 + grr * 16;
  int w0 = gc * 16;
  int t = threadIdx.x;
  int xx = t >> 4, yy = t & 15;
  const unsigned short* xp =
      Xf + (size_t)b * 64 * 16384 + (hr0 + xx) * 64 + (w0 + yy);
  const float* lare = (reg == 0) ? la1re : la2re;
  const float* laim = (reg == 0) ? la1im : la2im;
  float ar0 = 0.f, ai0 = 0.f, ar1 = 0.f, ai1 = 0.f;
  float ar2 = 0.f, ai2 = 0.f, ar3 = 0.f, ai3 = 0.f;
#pragma unroll 8
  for (int i = 0; i < 64; ++i) {
    float xr = ubf(xp[(size_t)i * 16384]);
    float xi = ubf(xp[(size_t)i * 16384 + 8192]);
    float l0r = lare[(e * 4 + 0) * 64 + i], l0i = laim[(e * 4 + 0) * 64 + i];
    float l1r = lare[(e * 4 + 1) * 64 + i], l1i = laim[(e * 4 + 1) * 64 + i];
    float l2r = lare[(e * 4 + 2) * 64 + i], l2i = laim[(e * 4 + 2) * 64 + i];
    float l3r = lare[(e * 4 + 3) * 64 + i], l3i = laim[(e * 4 + 3) * 64 + i];
    ar0 += l0r * xr - l0i * xi; ai0 += l0r * xi + l0i * xr;
    ar1 += l1r * xr - l1i * xi; ai1 += l1r * xi + l1i * xr;
    ar2 += l2r * xr - l2i * xi; ai2 += l2r * xi + l2i * xr;
    ar3 += l3r * xr - l3i * xi; ai3 += l3r * xi + l3i * xr;
  }
  float2* dst = T + ((((size_t)reg * 15 + e) * 8 + b) * 256 + t) * 4;
  dst[0] = make_float2(ar0, ai0);
  dst[1] = make_float2(ar1, ai1);
  dst[2] = make_float2(ar2, ai2);
  dst[3] = make_float2(ar3, ai3);
}

// ---------------------------------------------------------------------------
// Fused stage C.2 + C.3 (kDM): blocks [0,256) run the dense-corner body (kD),
// blocks [256,768) run the LoRA body (kM). Bodies unchanged (bit-identical).
// ---------------------------------------------------------------------------
__global__ __launch_bounds__(256) void kDM(const unsigned short* __restrict__ Xf,
                                           const float2* __restrict__ T,
                                           unsigned short* __restrict__ Gt,
                                           const float* __restrict__ w1re,
                                           const float* __restrict__ w1im,
                                           const float* __restrict__ w2re,
                                           const float* __restrict__ w2im,
                                           const float* __restrict__ lb1re,
                                           const float* __restrict__ lb1im,
                                           const float* __restrict__ lb2re,
                                           const float* __restrict__ lb2im,
                                           const float* __restrict__ gate1,
                                           const float* __restrict__ gate2) {
  __shared__ unsigned Xs[32 * 4 * 8 * 8];    // 32 KB (used by dense body only)
  if (blockIdx.x < 256) {
    // ---- dense body (kD) ----
    int bid = blockIdx.x;
    int yc = bid & 1, xc = (bid >> 1) & 3, oc = (bid >> 3) & 15, reg = bid >> 7;
    int hrb = (reg == 0) ? xc * 4 : 112 + xc * 4;
    const float* Wre = (reg == 0) ? w1re : w2re;
    const float* Wim = (reg == 0) ? w1im : w2im;
    int t = threadIdx.x;
    int b = t >> 5, o = (t >> 3) & 3, yy = t & 7;
    int og = oc * 4 + o, yyg = yc * 8 + yy;
    float ar[4] = {0.f, 0.f, 0.f, 0.f}, ai[4] = {0.f, 0.f, 0.f, 0.f};
    for (int ch = 0; ch < 2; ++ch) {
      __syncthreads();
#pragma unroll
      for (int j = 0; j < 4; ++j) {
        int seg = t + j * 256;               // 0..1023 = (sb 8, sx 4, si 32)
        int sb = seg >> 7, sx = (seg >> 5) & 3, si = seg & 31;
        int i = ch * 32 + si;
        const unsigned short* p =
            Xf + (size_t)(sb * 64 + i) * 16384 + (hrb + sx) * 64 + yc * 8;
        uint4 re = *(const uint4*)p;          // 8 yy re
        uint4 im = *(const uint4*)(p + 8192); // 8 yy im
        uint4 o0, o1;
        o0.x = (re.x & 0xFFFFu) | (im.x << 16);
        o0.y = (re.x >> 16) | (im.x & 0xFFFF0000u);
        o0.z = (re.y & 0xFFFFu) | (im.y << 16);
        o0.w = (re.y >> 16) | (im.y & 0xFFFF0000u);
        o1.x = (re.z & 0xFFFFu) | (im.z << 16);
        o1.y = (re.z >> 16) | (im.z & 0xFFFF0000u);
        o1.z = (re.w & 0xFFFFu) | (im.w << 16);
        o1.w = (re.w >> 16) | (im.w & 0xFFFF0000u);
        uint4* d = (uint4*)&Xs[((si * 4 + sx) * 8 + sb) * 8];
        d[0] = o0; d[1] = o1;
      }
      __syncthreads();
      for (int ic = 0; ic < 32; ++ic) {
        int i = ch * 32 + ic;
#pragma unroll
        for (int xs = 0; xs < 4; ++xs) {
          unsigned pk = Xs[((ic * 4 + xs) * 8 + b) * 8 + yy];
          float xr = ubf((unsigned short)(pk & 0xFFFFu));
          float xi = ubf((unsigned short)(pk >> 16));
          int widx = ((i * 64 + og) * 16 + xc * 4 + xs) * 16 + yyg;
          float wr = Wre[widx], wi = Wim[widx];
          ar[xs] += xr * wr - xi * wi;
          ai[xs] += xr * wi + xi * wr;
        }
      }
    }
    uint4 ov;
    ov.x = pk2(ar[0], ai[0]);
    ov.y = pk2(ar[1], ai[1]);
    ov.z = pk2(ar[2], ai[2]);
    ov.w = pk2(ar[3], ai[3]);
    *(uint4*)(Gt + ((size_t)(b * 64 + og) * 64 + yyg) * 256 + 2 * hrb) = ov;
  } else {
    // ---- LoRA body (kM) ----
    int bid = blockIdx.x - 256;
    int xc = bid & 3, hrc = (bid >> 2) & 7, oc = bid >> 5;
    int t = threadIdx.x;
    int w = t & 63, og = t >> 6;
    int o = oc * 4 + og;
    int reg = hrc >> 2;
    int grr = hrc & 3;
    int gc = w >> 4, yy = w & 15;
    int e = (reg == 0) ? (4 * grr + gc - 1) : (4 * (3 - grr) + gc - 1);
    if (e < 0) return;                       // dense cell -> dense body writes it
    float gate = (reg == 0) ? gate1[e] : gate2[e];
    float g = 0.1f / (1.f + __expf(-gate));
    const float* lbre = (reg == 0) ? lb1re : lb2re;
    const float* lbim = (reg == 0) ? lb1im : lb2im;
    size_t lbb = ((size_t)(e * 64 + o) * 4) * 256 + yy;
    float blr[4][4], bli[4][4];
#pragma unroll
    for (int x2 = 0; x2 < 4; ++x2) {
      int xx = xc * 4 + x2;
      const float* pr = lbre + lbb + xx * 16;
      const float* pi = lbim + lbb + xx * 16;
#pragma unroll
      for (int r = 0; r < 4; ++r) {
        blr[x2][r] = pr[r * 256];
        bli[x2][r] = pi[r * 256];
      }
    }
    const size_t tbase = (((size_t)reg * 15 + e) * 8) * 256 + yy;
    for (int b = 0; b < 8; ++b) {
      const float4* tp = (const float4*)(T + (tbase + (size_t)b * 256) * 4);
      unsigned out4[4];
#pragma unroll
      for (int x2 = 0; x2 < 4; ++x2) {
        int xx = xc * 4 + x2;
        float4 t01 = tp[xx * 32];            // r0, r1 (re,im pairs)
        float4 t23 = tp[xx * 32 + 1];        // r2, r3
        float ar = 0.f, aim = 0.f;
        ar += t01.x * blr[x2][0] - t01.y * bli[x2][0];
        aim += t01.x * bli[x2][0] + t01.y * blr[x2][0];
        ar += t01.z * blr[x2][1] - t01.w * bli[x2][1];
        aim += t01.z * bli[x2][1] + t01.w * blr[x2][1];
        ar += t23.x * blr[x2][2] - t23.y * bli[x2][2];
        aim += t23.x * bli[x2][2] + t23.y * blr[x2][2];
        ar += t23.z * blr[x2][3] - t23.w * bli[x2][3];
        aim += t23.z * bli[x2][3] + t23.w * blr[x2][3];
        out4[x2] = pk2(g * ar, g * aim);
      }
      *(uint4*)(Gt + ((size_t)(b * 64 + o) * 64 + w) * 256 + hrc * 32 + xc * 8) =
          make_uint4(out4[0], out4[1], out4[2], out4[3]);
    }
  }
}

// ---------------------------------------------------------------------------
// Fused stages D+E (kDE): per (b,o), 512 blocks x 512 thr.
// Round-7 phase 1: counted-vmcnt double-buffered DMA staging (same pattern
// as kAB). S bufs 36 KB each (TD 32K + Gt 4K); ZL 68K aliases them in
// phase 2; Bs2 8K at 72K. Total 80 KB -> 2 blocks/CU.
// Phase 2 unchanged (4 short kk with syncthreads drains — cheap).
// ---------------------------------------------------------------------------
__global__ __launch_bounds__(512) void kDE(const unsigned short* __restrict__ Gt,
                                           const unsigned short* __restrict__ TD,
                                           const unsigned short* __restrict__ TEt,
                                           float* __restrict__ y) {
  __shared__ __align__(16) char smem[81920];
  // S[i] halfword base: i*18432 (36 KB). Layout: TD @0 (16384 hw), Gt @16384 (2048 hw)
  unsigned short* Sb  = (unsigned short*)smem;
  unsigned short* ZL  = (unsigned short*)smem;            // [256*136] 68 KB (phase 2)
  unsigned short* Bs2 = (unsigned short*)(smem + 73728);  // [128*32]   8 KB (phase 2)
  int t = threadIdx.x, lane = t & 63, wid = t >> 6;
  int bo = blockIdx.x;
  const unsigned short* Grow = Gt + (size_t)bo * 16384;
  int lrow = lane & 15, lk = (lane >> 4) * 8, jhi = lane >> 4;

  // ---- phase 1: Z = TD * Gt, counted-vmcnt dbuf ----
  {
    int mb = wid * 64;
    f32x4 acc[4][4];
#pragma unroll
    for (int a = 0; a < 4; ++a)
#pragma unroll
      for (int b = 0; b < 4; ++b) acc[a][b] = (f32x4){0.f, 0.f, 0.f, 0.f};
    // prologue: stage(0) -> S0
#pragma unroll
    for (int j = 0; j < 4; ++j) {            // TD tile 512x32: 4 gload16/thread
      int c = j * 512 + t;
      int m = c >> 2, s2 = c & 3;
      gload16(&TD[m * 256 + ((s2 ^ (m & 3))) * 8], &Sb[c * 8]);
    }
    if (t < 256) {                           // Gt tile 64x32: 1 gload16 (waves 0-3)
      int n = t >> 2, s2 = t & 3;
      gload16(&Grow[n * 256 + ((s2 ^ (n & 3))) * 8], &Sb[16384 + t * 8]);
    }
#pragma unroll
    for (int kk = 0; kk < 8; ++kk) {
      int cur = kk & 1;
      unsigned short* Scur = Sb + cur * 18432;
      unsigned short* Snxt = Sb + (cur ^ 1) * 18432;
      __builtin_amdgcn_s_barrier();                 // BAR_A
      __builtin_amdgcn_sched_barrier(0);
      if (kk < 7) {
        int k1 = (kk + 1) * 32;
#pragma unroll
        for (int j = 0; j < 4; ++j) {
          int c = j * 512 + t;
          int m = c >> 2, s2 = c & 3;
          gload16(&TD[m * 256 + k1 + ((s2 ^ (m & 3))) * 8], &Snxt[c * 8]);
        }
        if (t < 256) {
          int n = t >> 2, s2 = t & 3;
          gload16(&Grow[n * 256 + k1 + ((s2 ^ (n & 3))) * 8], &Snxt[16384 + t * 8]);
          asm volatile("s_waitcnt vmcnt(5)" ::: "memory");   // wave-uniform branch
        } else {
          asm volatile("s_waitcnt vmcnt(4)" ::: "memory");
        }
      } else {
        asm volatile("s_waitcnt vmcnt(0)" ::: "memory");
      }
      __builtin_amdgcn_sched_barrier(0);
      __builtin_amdgcn_s_barrier();                 // BAR_B
      __builtin_amdgcn_sched_barrier(0);
      short8 af[4], bf[4];
#pragma unroll
      for (int a = 0; a < 4; ++a) {
        int row = mb + a * 16 + lrow;
        af[a] = *(const short8*)&Scur[row * 32 + ((jhi ^ (row & 3))) * 8];
      }
#pragma unroll
      for (int b = 0; b < 4; ++b) {
        int row = b * 16 + lrow;
        bf[b] = *(const short8*)&Scur[16384 + row * 32 + ((jhi ^ (row & 3))) * 8];
      }
#pragma unroll
      for (int a = 0; a < 4; ++a)
#pragma unroll
        for (int b = 0; b < 4; ++b)
          acc[a][b] = __builtin_amdgcn_mfma_f32_16x16x32_bf16(af[a], bf[b], acc[a][b], 0, 0, 0);
    }
    // write Z (bf16) into ZL[p][k=2w+pl], stride 136 (staging dead after drain)
    __syncthreads();
#pragma unroll
    for (int a = 0; a < 4; ++a)
#pragma unroll
      for (int b = 0; b < 4; ++b)
#pragma unroll
        for (int r = 0; r < 4; ++r) {
          int m = mb + a * 16 + (lane >> 4) * 4 + r;
          int p = m & 255, pl = m >> 8;
          int n = b * 16 + lrow;
          ZL[p * 136 + 2 * n + pl] = (unsigned short)bf16u(acc[a][b][r]);
        }
    __syncthreads();
  }

  // ---- phase 2: y = ZL * TEt^T, qh in {0,1} ----
  int mb2 = (wid >> 1) * 64, nb2 = (wid & 1) * 64;
  for (int qh = 0; qh < 2; ++qh) {
    f32x4 acc[4][4];
#pragma unroll
    for (int a = 0; a < 4; ++a)
#pragma unroll
      for (int b = 0; b < 4; ++b) acc[a][b] = (f32x4){0.f, 0.f, 0.f, 0.f};
    for (int kk = 0; kk < 4; ++kk) {
      int k0 = kk * 32;
      __syncthreads();
      {                                        // TEt tile 128x32 via DMA
        int n = t >> 2, s2 = t & 3;
        gload16(&TEt[(qh * 128 + n) * 128 + k0 + ((s2 ^ (n & 3))) * 8], &Bs2[t * 8]);
      }
      __syncthreads();
      short8 af[4], bf[4];
#pragma unroll
      for (int a = 0; a < 4; ++a)
        af[a] = *(const short8*)&ZL[(mb2 + a * 16 + lrow) * 136 + k0 + lk];
#pragma unroll
      for (int b = 0; b < 4; ++b) {
        int row = nb2 + b * 16 + lrow;
        bf[b] = *(const short8*)&Bs2[row * 32 + ((jhi ^ (row & 3))) * 8];
      }
#pragma unroll
      for (int a = 0; a < 4; ++a)
#pragma unroll
        for (int b = 0; b < 4; ++b)
          acc[a][b] = __builtin_amdgcn_mfma_f32_16x16x32_bf16(af[a], bf[b], acc[a][b], 0, 0, 0);
    }
    float* dst = y + (size_t)bo * 65536 + qh * 128;
#pragma unroll
    for (int a = 0; a < 4; ++a)
#pragma unroll
      for (int b = 0; b < 4; ++b)
#pragma unroll
        for (int r = 0; r < 4; ++r) {
          int p = mb2 + a * 16 + (lane >> 4) * 4 + r;
          int q = nb2 + b * 16 + lrow;
          dst[(size_t)p * 256 + q] = acc[a][b][r];
        }
  }
}

// ---------------------------------------------------------------------------
// sploss = mean(sigmoid(gate1)) + mean(sigmoid(gate2))  (fp32)
// ---------------------------------------------------------------------------
__global__ void kS2(const float* __restrict__ gate1, const float* __restrict__ gate2,
                    float* __restrict__ out) {
  if (threadIdx.x == 0) {
    float s = 0.f;
    for (int e = 0; e < NE_; ++e)
      s += 1.f / (1.f + expf(-gate1[e])) + 1.f / (1.f + expf(-gate2[e]));
    out[0] = s / (float)NE_;
  }
}

extern "C" void kernel_launch(void* const* d_in, const int* in_sizes, int n_in,
                              void* d_out, int out_size, void* d_ws, size_t ws_size,
                              hipStream_t stream) {
  const float* x     = (const float*)d_in[0];
  const float* w1re  = (const float*)d_in[1];
  const float* w1im  = (const float*)d_in[2];
  const float* w2re  = (const float*)d_in[3];
  const float* w2im  = (const float*)d_in[4];
  const float* la1re = (const float*)d_in[5];
  const float* la1im = (const float*)d_in[6];
  const float* lb1re = (const float*)d_in[7];
  const float* lb1im = (const float*)d_in[8];
  const float* la2re = (const float*)d_in[9];
  const float* la2im = (const float*)d_in[10];
  const float* lb2re = (const float*)d_in[11];
  const float* lb2im = (const float*)d_in[12];
  const float* gate1 = (const float*)d_in[13];
  const float* gate2 = (const float*)d_in[14];

  // Workspace layout (bf16 halfwords):
  //   Xf  @ 32 MiB : [b,i][m=hr-plane 256][w 64] 16 MiB
  //   Gt  @ 48 MiB : [b,o][w 64][k=2hr+pl 256]   16 MiB
  //   tables @ 96 MiB : TAt 64K, TB 256K, TD 256K, TEt 64K  (1.25 MiB)
  //   T   @ 97 MiB : [reg][e][b][xy][r] float2   ~2 MiB
  char* ws = (char*)d_ws;
  unsigned short* Xf  = (unsigned short*)(ws + ((size_t)32 << 20));
  unsigned short* Gt  = (unsigned short*)(ws + ((size_t)48 << 20));
  unsigned short* TAt = (unsigned short*)(ws + ((size_t)96 << 20));
  unsigned short* TB  = TAt + 32768;
  unsigned short* TD  = TB + 131072;
  unsigned short* TEt = TD + 131072;
  float2* Tw = (float2*)(ws + ((size_t)97 << 20));
  float* y = (float*)d_out;

  kTab<<<1280, 256, 0, stream>>>(TAt, TB, TD, TEt);
  kAB<<<512, 512, 0, stream>>>(x, TAt, TB, Xf);
  kT<<<240, 256, 0, stream>>>(Xf, Tw, la1re, la1im, la2re, la2im);
  kDM<<<768, 256, 0, stream>>>(Xf, Tw, Gt, w1re, w1im, w2re, w2im,
                               lb1re, lb1im, lb2re, lb2im, gate1, gate2);
  kDE<<<512, 512, 0, stream>>>(Gt, TD, TEt, y);
  kS2<<<1, 64, 0, stream>>>(gate1, gate2, y + (size_t)B_ * CO_ * H_ * W_);
}